// Round 1
// baseline (4499.467 us; speedup 1.0000x reference)
//
#include <hip/hip_runtime.h>
#include <hip/hip_bf16.h>
#include <stdint.h>
#include <stddef.h>

#define RROWS 55120   // 8*6890 rows
#define DIN   352
#define DP    384     // padded channel dim
#define NBLK  7
#define KD    120     // eigenbasis size
#define BATCH 8
#define NVERT 6890
#define BN_EPS 1e-3f

typedef __attribute__((ext_vector_type(8))) short short8;
typedef __attribute__((ext_vector_type(4))) float floatx4;

__device__ __forceinline__ short f2bf(float f) {
  union { float f; uint32_t u; } v; v.f = f;
  uint32_t r = (v.u + 0x7fffu + ((v.u >> 16) & 1u)) >> 16;  // RNE
  return (short)r;
}
__device__ __forceinline__ float bf2f(short s) {
  union { uint32_t u; float f; } v; v.u = ((uint32_t)(uint16_t)s) << 16;
  return v.f;
}

// ---------------------------------------------------------------------------
// Weight prep: Wt[blk][n][k] = bf16(W[blk][k][n]), zero-padded 352->384
// ---------------------------------------------------------------------------
__global__ __launch_bounds__(256) void prep_w(const float* __restrict__ W1, const float* __restrict__ W2,
                                              short* __restrict__ W1t, short* __restrict__ W2t) {
  int e = blockIdx.x * 256 + threadIdx.x;
  const float* W = blockIdx.y ? W2 : W1;
  short* Wt = blockIdx.y ? W2t : W1t;
  int blk = e / (DP * DP);
  int rem = e - blk * DP * DP;
  int n = rem / DP;
  int k = rem - n * DP;
  float v = (n < DIN && k < DIN) ? W[(size_t)blk * DIN * DIN + (size_t)k * DIN + n] : 0.f;
  Wt[e] = f2bf(v);
}

// ---------------------------------------------------------------------------
// cast input fp32 -> bf16, pad channels to 384; block 0 zeroes statsA
// thread layout: 192 thr = 48 channel-groups x 4 rows; per-thread fixed channels
// ---------------------------------------------------------------------------
__global__ __launch_bounds__(192) void cast_in(const float* __restrict__ F, short* __restrict__ X,
                                               float* __restrict__ zbuf) {
  int tid = threadIdx.x;
  if (blockIdx.x == 0)
    for (int z = tid; z < 2 * DP; z += 192) zbuf[z] = 0.f;
  int cg = tid % 48, rl = tid / 48;
  int c0 = cg * 8;
  int row0 = blockIdx.x * 128;
  for (int rr = rl; rr < 128; rr += 4) {
    int row = row0 + rr;
    if (row >= RROWS) break;
    short8 o;
    if (c0 < DIN) {
      const float* src = F + (size_t)row * DIN + c0;
      #pragma unroll
      for (int j = 0; j < 8; ++j) o[j] = f2bf(src[j]);
    } else {
      #pragma unroll
      for (int j = 0; j < 8; ++j) o[j] = 0;
    }
    *(short8*)(X + (size_t)row * DP + c0) = o;
  }
}

// ---------------------------------------------------------------------------
// GEMM: Y[m][n] = A[m][:] @ Wt[n][:] + bias[n]   (bf16 in, bf16 out, fp32 acc)
// fused per-column sum / sumsq atomically into stats[0..DP-1], stats[DP..2DP-1]
// 128x128 tile, BK=64, global_load_lds staging with XOR granule swizzle.
// ---------------------------------------------------------------------------
__global__ __launch_bounds__(256) void gemm_bn(
    const short* __restrict__ A, const short* __restrict__ Bt,
    short* __restrict__ Y, const float* __restrict__ bias,
    float* __restrict__ stats) {
  __shared__ short As[128 * 64];
  __shared__ short Bs[128 * 64];
  const int tid = threadIdx.x;
  const int lane = tid & 63;
  const int w = tid >> 6;
  const int m0 = blockIdx.x * 128;
  const int n0 = blockIdx.y * 128;

  // staging: wave w covers rows 32w..32w+31 per tile (4 instr x 8 rows)
  // lane l -> row rsub=(l>>3), fetches global granule (l&7)^rsub  (XOR swizzle)
  const int rsub = lane >> 3;
  const int gsw = (lane & 7) ^ rsub;

  const short* aSrc[4]; const short* bSrc[4];
  short* aDst[4]; short* bDst[4];
  #pragma unroll
  for (int t = 0; t < 4; ++t) {
    int r = 32 * w + 8 * t + rsub;
    int gm = m0 + r; if (gm >= RROWS) gm = RROWS - 1;   // clamp ragged M tile
    aSrc[t] = A + (size_t)gm * DP + gsw * 8;
    bSrc[t] = Bt + (size_t)(n0 + r) * DP + gsw * 8;
    aDst[t] = &As[(32 * w + 8 * t) * 64];   // wave-uniform LDS base
    bDst[t] = &Bs[(32 * w + 8 * t) * 64];
  }

  floatx4 acc[4][4];
  #pragma unroll
  for (int i = 0; i < 4; ++i)
    #pragma unroll
    for (int j = 0; j < 4; ++j)
      acc[i][j] = (floatx4){0.f, 0.f, 0.f, 0.f};

  const int l15 = lane & 15;
  const int q = lane >> 4;
  const int wm = 64 * (w >> 1);
  const int wn = 64 * (w & 1);

  for (int kt = 0; kt < DP / 64; ++kt) {
    __syncthreads();   // previous iter's ds_reads done -> LDS reusable
    #pragma unroll
    for (int t = 0; t < 4; ++t) {
      __builtin_amdgcn_global_load_lds((const __attribute__((address_space(1))) void*)(aSrc[t] + kt * 64),
                                       (__attribute__((address_space(3))) void*)aDst[t], 16, 0, 0);
      __builtin_amdgcn_global_load_lds((const __attribute__((address_space(1))) void*)(bSrc[t] + kt * 64),
                                       (__attribute__((address_space(3))) void*)bDst[t], 16, 0, 0);
    }
    __syncthreads();   // compiler drains vmcnt before barrier
    #pragma unroll
    for (int ks = 0; ks < 2; ++ks) {
      const int pos8 = ((((ks << 2) | q)) ^ (l15 & 7)) * 8;  // unswizzle on read
      short8 af[4], bfv[4];
      #pragma unroll
      for (int mt = 0; mt < 4; ++mt)
        af[mt] = *(const short8*)&As[(wm + 16 * mt + l15) * 64 + pos8];
      #pragma unroll
      for (int nt = 0; nt < 4; ++nt)
        bfv[nt] = *(const short8*)&Bs[(wn + 16 * nt + l15) * 64 + pos8];
      #pragma unroll
      for (int mt = 0; mt < 4; ++mt)
        #pragma unroll
        for (int nt = 0; nt < 4; ++nt)
          acc[mt][nt] = __builtin_amdgcn_mfma_f32_16x16x32_bf16(af[mt], bfv[nt], acc[mt][nt], 0, 0, 0);
    }
  }

  // epilogue: bias add, bf16 store, per-column stats (C/D: col=lane&15, row=q*4+v)
  const int mwb = m0 + wm;
  const int nwb = n0 + wn;
  #pragma unroll
  for (int nt = 0; nt < 4; ++nt) {
    const int n = nwb + 16 * nt + l15;
    const float bv = (n < DIN) ? bias[n] : 0.f;
    float s1 = 0.f, s2 = 0.f;
    #pragma unroll
    for (int mt = 0; mt < 4; ++mt) {
      const int mb = mwb + 16 * mt + 4 * q;
      #pragma unroll
      for (int v = 0; v < 4; ++v) {
        const int m = mb + v;
        if (m < RROWS) {
          float val = acc[mt][nt][v] + bv;
          Y[(size_t)m * DP + n] = f2bf(val);
          s1 += val;
          s2 += val * val;
        }
      }
    }
    s1 += __shfl_xor(s1, 16);
    s2 += __shfl_xor(s2, 16);
    s1 += __shfl_xor(s1, 32);
    s2 += __shfl_xor(s2, 32);
    if (q == 0) {
      atomicAdd(&stats[n], s1);
      atomicAdd(&stats[DP + n], s2);
    }
  }
}

// ---------------------------------------------------------------------------
// ELT1: H = relu(gamma*(Y-mean)*istd + beta); zeroes the other stats buffer
// ---------------------------------------------------------------------------
__global__ __launch_bounds__(192) void elt_bn(
    const short* __restrict__ Yin, short* __restrict__ Hout,
    const float* __restrict__ stats, const float* __restrict__ gamma, const float* __restrict__ beta,
    float* __restrict__ zbuf) {
  int tid = threadIdx.x;
  if (blockIdx.x == 0)
    for (int z = tid; z < 2 * DP; z += 192) zbuf[z] = 0.f;
  int cg = tid % 48, rl = tid / 48;
  int c0 = cg * 8;
  float av[8], bb[8];
  #pragma unroll
  for (int j = 0; j < 8; ++j) {
    int c = c0 + j;
    float mean = stats[c] * (1.f / RROWS);
    float var = stats[DP + c] * (1.f / RROWS) - mean * mean;
    float istd = rsqrtf(var + BN_EPS);
    float g = (c < DIN) ? gamma[c] : 0.f;
    float b = (c < DIN) ? beta[c] : 0.f;
    av[j] = g * istd;
    bb[j] = b - g * istd * mean;
  }
  int row0 = blockIdx.x * 128;
  for (int rr = rl; rr < 128; rr += 4) {
    int row = row0 + rr;
    if (row >= RROWS) break;
    size_t off = (size_t)row * DP + c0;
    short8 y = *(const short8*)(Yin + off);
    short8 h;
    #pragma unroll
    for (int j = 0; j < 8; ++j) {
      float v = av[j] * bf2f(y[j]) + bb[j];
      h[j] = f2bf(fmaxf(v, 0.f));
    }
    *(short8*)(Hout + off) = h;
  }
}

// ---------------------------------------------------------------------------
// ELT2: X = relu(bn(Y) + X); optional fp32 write of result into d_out
// ---------------------------------------------------------------------------
__global__ __launch_bounds__(192) void elt_res(
    const short* __restrict__ Yin, short* __restrict__ X,
    const float* __restrict__ stats, const float* __restrict__ gamma, const float* __restrict__ beta,
    float* __restrict__ zbuf, float* __restrict__ fout) {
  int tid = threadIdx.x;
  if (blockIdx.x == 0)
    for (int z = tid; z < 2 * DP; z += 192) zbuf[z] = 0.f;
  int cg = tid % 48, rl = tid / 48;
  int c0 = cg * 8;
  float av[8], bb[8];
  #pragma unroll
  for (int j = 0; j < 8; ++j) {
    int c = c0 + j;
    float mean = stats[c] * (1.f / RROWS);
    float var = stats[DP + c] * (1.f / RROWS) - mean * mean;
    float istd = rsqrtf(var + BN_EPS);
    float g = (c < DIN) ? gamma[c] : 0.f;
    float b = (c < DIN) ? beta[c] : 0.f;
    av[j] = g * istd;
    bb[j] = b - g * istd * mean;
  }
  int row0 = blockIdx.x * 128;
  for (int rr = rl; rr < 128; rr += 4) {
    int row = row0 + rr;
    if (row >= RROWS) break;
    size_t off = (size_t)row * DP + c0;
    short8 y = *(const short8*)(Yin + off);
    short8 x = *(const short8*)(X + off);
    short8 h;
    float vr[8];
    #pragma unroll
    for (int j = 0; j < 8; ++j) {
      float v = av[j] * bf2f(y[j]) + bb[j] + bf2f(x[j]);
      v = fmaxf(v, 0.f);
      vr[j] = v;
      h[j] = f2bf(v);
    }
    *(short8*)(X + off) = h;
    if (fout != nullptr && c0 < DIN) {
      float4 o0 = make_float4(vr[0], vr[1], vr[2], vr[3]);
      float4 o1 = make_float4(vr[4], vr[5], vr[6], vr[7]);
      *(float4*)(fout + (size_t)row * DIN + c0) = o0;
      *(float4*)(fout + (size_t)row * DIN + c0 + 4) = o1;
    }
  }
}

// ---------------------------------------------------------------------------
// Fh: Fo[u][v] = sum_n E[n][u] * Xf[n][v]   (= Fh^T per batch), fp32, atomic acc
// grid: x = vtile(11) * nchunk(8), y = batch, z = feature
// ---------------------------------------------------------------------------
#define FH_NCH 8
__global__ __launch_bounds__(256) void fh_kern(
    const float* __restrict__ evx, const float* __restrict__ evy,
    const float* __restrict__ outbuf, float* __restrict__ Fh) {
  __shared__ float Es[32 * 120];
  __shared__ float Xs[32 * 33];
  int f = blockIdx.z, b = blockIdx.y;
  int vt = blockIdx.x % 11, nc = blockIdx.x / 11;
  const float* E = (f ? evy : evx) + (size_t)b * NVERT * KD;
  const float* Xf = outbuf + 2 * BATCH * KD * KD + (size_t)f * RROWS * DIN + (size_t)b * NVERT * DIN;
  float* Fo = Fh + ((size_t)(f * BATCH + b)) * KD * DIN;
  const int chunk = (NVERT + FH_NCH - 1) / FH_NCH;  // 862
  int nstart = nc * chunk;
  int nend = nstart + chunk; if (nend > NVERT) nend = NVERT;
  int tid = threadIdx.x;
  int tu = tid >> 5, tv = tid & 31;
  int v0 = vt * 32;
  float acc[15];
  #pragma unroll
  for (int i = 0; i < 15; ++i) acc[i] = 0.f;
  for (int ns = nstart; ns < nend; ns += 32) {
    __syncthreads();
    #pragma unroll
    for (int j = 0; j < 15; ++j) {
      int e = tid + 256 * j;
      int r = e / 120, c = e - r * 120;
      int row = ns + r;
      Es[e] = (row < nend) ? E[(size_t)row * KD + c] : 0.f;
    }
    #pragma unroll
    for (int j = 0; j < 4; ++j) {
      int e = tid + 256 * j;
      int r = e >> 5, c = e & 31;
      Xs[r * 33 + c] = (ns + r < nend) ? Xf[(size_t)(ns + r) * DIN + v0 + c] : 0.f;
    }
    __syncthreads();
    #pragma unroll 4
    for (int n = 0; n < 32; ++n) {
      float xv = Xs[n * 33 + tv];
      #pragma unroll
      for (int i = 0; i < 15; ++i)
        acc[i] += Es[n * 120 + tu + 8 * i] * xv;
    }
  }
  #pragma unroll
  for (int i = 0; i < 15; ++i)
    atomicAdd(&Fo[(size_t)(tu + 8 * i) * DIN + v0 + tv], acc[i]);
}

// ---------------------------------------------------------------------------
// Gram: mat0=FtF=Fx·Fxᵀ, mat1=FtG=Fx·Fyᵀ, mat2=GtG=Fy·Fyᵀ (rows dot rows over d)
// ---------------------------------------------------------------------------
__global__ __launch_bounds__(256) void gram_kern(const float* __restrict__ Fh, float* __restrict__ G) {
  __shared__ float As[128 * 33];
  __shared__ float Bs[32 * 132];
  int mat = blockIdx.x, b = blockIdx.y;
  const float* Pa = Fh + (size_t)((mat == 2 ? BATCH : 0) + b) * KD * DIN;
  const float* Pb = Fh + (size_t)((mat == 0 ? 0 : BATCH) + b) * KD * DIN;
  int tid = threadIdx.x;
  int ty = tid >> 4, tx = tid & 15;
  float accv[8][8];
  #pragma unroll
  for (int i = 0; i < 8; ++i)
    #pragma unroll
    for (int j = 0; j < 8; ++j) accv[i][j] = 0.f;
  for (int ch = 0; ch < 11; ++ch) {
    int d0 = ch * 32;
    __syncthreads();
    #pragma unroll
    for (int j = 0; j < 16; ++j) {
      int e = tid + 256 * j;
      int r = e >> 5, c = e & 31;
      float va = (r < KD) ? Pa[(size_t)r * DIN + d0 + c] : 0.f;
      float vb = (r < KD) ? Pb[(size_t)r * DIN + d0 + c] : 0.f;
      As[r * 33 + c] = va;
      Bs[c * 132 + r] = vb;
    }
    __syncthreads();
    for (int dd = 0; dd < 32; ++dd) {
      float a[8], bv[8];
      #pragma unroll
      for (int i = 0; i < 8; ++i) a[i] = As[(8 * ty + i) * 33 + dd];
      float4 b0 = *(const float4*)&Bs[dd * 132 + 8 * tx];
      float4 b1 = *(const float4*)&Bs[dd * 132 + 8 * tx + 4];
      bv[0] = b0.x; bv[1] = b0.y; bv[2] = b0.z; bv[3] = b0.w;
      bv[4] = b1.x; bv[5] = b1.y; bv[6] = b1.z; bv[7] = b1.w;
      #pragma unroll
      for (int i = 0; i < 8; ++i)
        #pragma unroll
        for (int j = 0; j < 8; ++j)
          accv[i][j] += a[i] * bv[j];
    }
  }
  float* Go = G + (size_t)(b * 3 + mat) * KD * KD;
  #pragma unroll
  for (int i = 0; i < 8; ++i) {
    int k = 8 * ty + i;
    if (k < KD)
      #pragma unroll
      for (int j = 0; j < 8; ++j) {
        int l = 8 * tx + j;
        if (l < KD) Go[k * KD + l] = accv[i][j];
      }
  }
}

// ---------------------------------------------------------------------------
// Cholesky of FtF (sys even) / GtG (sys odd), in-LDS, L + invdiag to global
// ---------------------------------------------------------------------------
__global__ __launch_bounds__(128) void chol_kern(const float* __restrict__ G, float* __restrict__ Lb,
                                                 float* __restrict__ invd) {
  __shared__ float As[120 * 121];
  int sys = blockIdx.x;
  int b = sys >> 1;
  int mat = (sys & 1) ? 2 : 0;
  const float* Gm = G + (size_t)(b * 3 + mat) * KD * KD;
  int tid = threadIdx.x;
  for (int e = tid; e < KD * KD; e += 128) {
    int r = e / KD, c = e - r * KD;
    As[r * 121 + c] = Gm[e];
  }
  __syncthreads();
  for (int p = 0; p < KD; ++p) {
    if (tid == 0) As[p * 121 + p] = sqrtf(As[p * 121 + p]);
    __syncthreads();
    float dinv = 1.f / As[p * 121 + p];
    int i = p + 1 + tid;
    if (i < KD) As[i * 121 + p] *= dinv;
    __syncthreads();
    if (i < KD) {
      float lip = As[i * 121 + p];
      for (int jj = p + 1; jj <= i; ++jj)
        As[i * 121 + jj] -= lip * As[jj * 121 + p];
    }
    __syncthreads();
  }
  float* Lo = Lb + (size_t)sys * (KD * 121);
  for (int e = tid; e < KD * 121; e += 128) Lo[e] = As[e];
  if (tid < KD) invd[sys * KD + tid] = 1.f / As[tid * 121 + tid];
}

// ---------------------------------------------------------------------------
// Triangular solves: columns thread-private in LDS -> no barriers.
// sys even: X = FtF^-1 FtG, write C1 = X^T ; sys odd: X = GtG^-1 FtG^T, C2 = X^T
// ---------------------------------------------------------------------------
__global__ __launch_bounds__(128) void solve_kern(const float* __restrict__ Lb, const float* __restrict__ invd,
                                                  const float* __restrict__ G, float* __restrict__ out) {
  __shared__ float xs[120 * 128];
  int sys = blockIdx.x;
  int b = sys >> 1;
  int which = sys & 1;
  const float* L = Lb + (size_t)sys * (KD * 121);
  const float* iv = invd + sys * KD;
  const float* Bm = G + (size_t)(b * 3 + 1) * KD * KD;  // FtG
  int t = threadIdx.x;
  for (int k = 0; k < KD; ++k)
    xs[k * 128 + t] = (t < KD) ? (which == 0 ? Bm[k * KD + t] : Bm[t * KD + k]) : 0.f;
  // forward: L y = b
  for (int k = 0; k < KD; ++k) {
    float s0 = 0.f, s1 = 0.f, s2 = 0.f, s3 = 0.f;
    int j = 0;
    for (; j + 4 <= k; j += 4) {
      s0 += L[k * 121 + j + 0] * xs[(j + 0) * 128 + t];
      s1 += L[k * 121 + j + 1] * xs[(j + 1) * 128 + t];
      s2 += L[k * 121 + j + 2] * xs[(j + 2) * 128 + t];
      s3 += L[k * 121 + j + 3] * xs[(j + 3) * 128 + t];
    }
    for (; j < k; ++j) s0 += L[k * 121 + j] * xs[j * 128 + t];
    xs[k * 128 + t] = (xs[k * 128 + t] - ((s0 + s1) + (s2 + s3))) * iv[k];
  }
  // backward: L^T x = y
  for (int k = KD - 1; k >= 0; --k) {
    float s0 = 0.f, s1 = 0.f, s2 = 0.f, s3 = 0.f;
    int j = k + 1;
    for (; j + 4 <= KD; j += 4) {
      s0 += L[(j + 0) * 121 + k] * xs[(j + 0) * 128 + t];
      s1 += L[(j + 1) * 121 + k] * xs[(j + 1) * 128 + t];
      s2 += L[(j + 2) * 121 + k] * xs[(j + 2) * 128 + t];
      s3 += L[(j + 3) * 121 + k] * xs[(j + 3) * 128 + t];
    }
    for (; j < KD; ++j) s0 += L[j * 121 + k] * xs[j * 128 + t];
    xs[k * 128 + t] = (xs[k * 128 + t] - ((s0 + s1) + (s2 + s3))) * iv[k];
  }
  if (t < KD) {
    float* Co = out + (size_t)which * BATCH * KD * KD + (size_t)b * KD * KD;
    for (int k = 0; k < KD; ++k) Co[t * KD + k] = xs[k * 128 + t];  // transpose
  }
}

// ---------------------------------------------------------------------------
extern "C" void kernel_launch(void* const* d_in, const int* in_sizes, int n_in,
                              void* d_out, int out_size, void* d_ws, size_t ws_size,
                              hipStream_t stream) {
  (void)in_sizes; (void)n_in; (void)out_size; (void)ws_size;
  const float* feat_x = (const float*)d_in[0];
  const float* feat_y = (const float*)d_in[1];
  const float* evecs_x = (const float*)d_in[2];
  const float* evecs_y = (const float*)d_in[3];
  const float* W1 = (const float*)d_in[4];
  const float* b1 = (const float*)d_in[5];
  const float* W2 = (const float*)d_in[6];
  const float* b2 = (const float*)d_in[7];
  const float* gamma = (const float*)d_in[8];
  const float* beta = (const float*)d_in[9];
  float* out = (float*)d_out;

  char* p = (char*)d_ws;
  auto carve = [&](size_t bytes) { char* r = p; p += (bytes + 255) & ~(size_t)255; return r; };
  short* W1t = (short*)carve(7ull * DP * DP * 2);
  short* W2t = (short*)carve(7ull * DP * DP * 2);
  short* X  = (short*)carve((size_t)RROWS * DP * 2);
  short* T1 = (short*)carve((size_t)RROWS * DP * 2);
  short* T2 = (short*)carve((size_t)RROWS * DP * 2);
  float* stats = (float*)carve(4ull * DP * 4);
  float* Fh = (float*)carve(2ull * BATCH * KD * DIN * 4);
  float* gram = (float*)carve((size_t)BATCH * 3 * KD * KD * 4);
  float* Lb = (float*)carve(16ull * KD * 121 * 4);
  float* invd = (float*)carve(16ull * KD * 4);
  float* statsA = stats;
  float* statsB = stats + 2 * DP;

  hipMemsetAsync(Fh, 0, 2ull * BATCH * KD * DIN * 4, stream);
  prep_w<<<dim3((7 * DP * DP) / 256, 2), 256, 0, stream>>>(W1, W2, W1t, W2t);

  const int MT = (RROWS + 127) / 128;  // 431
  for (int f = 0; f < 2; ++f) {
    const float* feat = f ? feat_y : feat_x;
    float* fxo = out + 2 * BATCH * KD * KD + (size_t)f * RROWS * DIN;
    cast_in<<<MT, 192, 0, stream>>>(feat, X, statsA);
    for (int blk = 0; blk < NBLK; ++blk) {
      gemm_bn<<<dim3(MT, 3), 256, 0, stream>>>(X, W1t + (size_t)blk * DP * DP, T1, b1 + blk * DIN, statsA);
      elt_bn<<<MT, 192, 0, stream>>>(T1, T2, statsA, gamma + blk * DIN, beta + blk * DIN, statsB);
      gemm_bn<<<dim3(MT, 3), 256, 0, stream>>>(T2, W2t + (size_t)blk * DP * DP, T1, b2 + blk * DIN, statsB);
      elt_res<<<MT, 192, 0, stream>>>(T1, X, statsB, gamma + blk * DIN, beta + blk * DIN, statsA,
                                      (blk == NBLK - 1) ? fxo : (float*)nullptr);
    }
  }
  fh_kern<<<dim3(11 * FH_NCH, BATCH, 2), 256, 0, stream>>>(evecs_x, evecs_y, out, Fh);
  gram_kern<<<dim3(3, BATCH), 256, 0, stream>>>(Fh, gram);
  chol_kern<<<16, 128, 0, stream>>>(gram, Lb, invd);
  solve_kern<<<16, 128, 0, stream>>>(Lb, invd, gram, out);
}

// Round 2
// 4052.282 us; speedup vs baseline: 1.1104x; 1.1104x over previous
//
#include <hip/hip_runtime.h>
#include <hip/hip_bf16.h>
#include <stdint.h>
#include <stddef.h>

#define RROWS 55120   // 8*6890 rows
#define DIN   352
#define DP    384     // padded channel dim
#define NBLK  7
#define KD    120     // eigenbasis size
#define KDP   128     // padded
#define BATCH 8
#define NVERT 6890
#define BN_EPS 1e-3f
#define FH_S  16      // split-K chunks for Fh GEMM

typedef __attribute__((ext_vector_type(8))) short short8;
typedef __attribute__((ext_vector_type(4))) float floatx4;

__device__ __forceinline__ short f2bf(float f) {
  union { float f; uint32_t u; } v; v.f = f;
  uint32_t r = (v.u + 0x7fffu + ((v.u >> 16) & 1u)) >> 16;  // RNE
  return (short)r;
}
__device__ __forceinline__ float bf2f(short s) {
  union { uint32_t u; float f; } v; v.u = ((uint32_t)(uint16_t)s) << 16;
  return v.f;
}

// ---------------------------------------------------------------------------
// Weight prep: Wt[blk][n][k] = bf16(W[blk][k][n]), zero-padded 352->384
// ---------------------------------------------------------------------------
__global__ __launch_bounds__(256) void prep_w(const float* __restrict__ W1, const float* __restrict__ W2,
                                              short* __restrict__ W1t, short* __restrict__ W2t) {
  int e = blockIdx.x * 256 + threadIdx.x;
  const float* W = blockIdx.y ? W2 : W1;
  short* Wt = blockIdx.y ? W2t : W1t;
  int blk = e / (DP * DP);
  int rem = e - blk * DP * DP;
  int n = rem / DP;
  int k = rem - n * DP;
  float v = (n < DIN && k < DIN) ? W[(size_t)blk * DIN * DIN + (size_t)k * DIN + n] : 0.f;
  Wt[e] = f2bf(v);
}

// ---------------------------------------------------------------------------
// cast evecs fp32 [b][n][120] -> bf16 [b][n][128] (padded)
// ---------------------------------------------------------------------------
__global__ __launch_bounds__(256) void cast_e(const float* __restrict__ E, short* __restrict__ Eb) {
  int idx = blockIdx.x * 256 + threadIdx.x;
  int u8 = idx & 15;
  int n = idx >> 4;
  if (n >= NVERT) return;
  int b = blockIdx.y;
  short8 o;
  if (u8 < 15) {
    const float* src = E + ((size_t)b * NVERT + n) * KD + u8 * 8;
    #pragma unroll
    for (int j = 0; j < 8; ++j) o[j] = f2bf(src[j]);
  } else {
    #pragma unroll
    for (int j = 0; j < 8; ++j) o[j] = 0;
  }
  *(short8*)(Eb + ((size_t)b * NVERT + n) * KDP + u8 * 8) = o;
}

// ---------------------------------------------------------------------------
// cast input fp32 -> bf16, pad channels to 384; block 0 zeroes statsA
// ---------------------------------------------------------------------------
__global__ __launch_bounds__(192) void cast_in(const float* __restrict__ F, short* __restrict__ X,
                                               float* __restrict__ zbuf) {
  int tid = threadIdx.x;
  if (blockIdx.x == 0)
    for (int z = tid; z < 2 * DP; z += 192) zbuf[z] = 0.f;
  int cg = tid % 48, rl = tid / 48;
  int c0 = cg * 8;
  int row0 = blockIdx.x * 128;
  for (int rr = rl; rr < 128; rr += 4) {
    int row = row0 + rr;
    if (row >= RROWS) break;
    short8 o;
    if (c0 < DIN) {
      const float* src = F + (size_t)row * DIN + c0;
      #pragma unroll
      for (int j = 0; j < 8; ++j) o[j] = f2bf(src[j]);
    } else {
      #pragma unroll
      for (int j = 0; j < 8; ++j) o[j] = 0;
    }
    *(short8*)(X + (size_t)row * DP + c0) = o;
  }
}

// ---------------------------------------------------------------------------
// GEMM: Y[m][n] = A[m][:] @ Wt[n][:] + bias[n]   (bf16 in, bf16 out, fp32 acc)
// fused per-column sum / sumsq atomically into stats
// ---------------------------------------------------------------------------
__global__ __launch_bounds__(256) void gemm_bn(
    const short* __restrict__ A, const short* __restrict__ Bt,
    short* __restrict__ Y, const float* __restrict__ bias,
    float* __restrict__ stats) {
  __shared__ short As[128 * 64];
  __shared__ short Bs[128 * 64];
  const int tid = threadIdx.x;
  const int lane = tid & 63;
  const int w = tid >> 6;
  const int m0 = blockIdx.x * 128;
  const int n0 = blockIdx.y * 128;

  const int rsub = lane >> 3;
  const int gsw = (lane & 7) ^ rsub;

  const short* aSrc[4]; const short* bSrc[4];
  short* aDst[4]; short* bDst[4];
  #pragma unroll
  for (int t = 0; t < 4; ++t) {
    int r = 32 * w + 8 * t + rsub;
    int gm = m0 + r; if (gm >= RROWS) gm = RROWS - 1;
    aSrc[t] = A + (size_t)gm * DP + gsw * 8;
    bSrc[t] = Bt + (size_t)(n0 + r) * DP + gsw * 8;
    aDst[t] = &As[(32 * w + 8 * t) * 64];
    bDst[t] = &Bs[(32 * w + 8 * t) * 64];
  }

  floatx4 acc[4][4];
  #pragma unroll
  for (int i = 0; i < 4; ++i)
    #pragma unroll
    for (int j = 0; j < 4; ++j)
      acc[i][j] = (floatx4){0.f, 0.f, 0.f, 0.f};

  const int l15 = lane & 15;
  const int q = lane >> 4;
  const int wm = 64 * (w >> 1);
  const int wn = 64 * (w & 1);

  for (int kt = 0; kt < DP / 64; ++kt) {
    __syncthreads();
    #pragma unroll
    for (int t = 0; t < 4; ++t) {
      __builtin_amdgcn_global_load_lds((const __attribute__((address_space(1))) void*)(aSrc[t] + kt * 64),
                                       (__attribute__((address_space(3))) void*)aDst[t], 16, 0, 0);
      __builtin_amdgcn_global_load_lds((const __attribute__((address_space(1))) void*)(bSrc[t] + kt * 64),
                                       (__attribute__((address_space(3))) void*)bDst[t], 16, 0, 0);
    }
    __syncthreads();
    #pragma unroll
    for (int ks = 0; ks < 2; ++ks) {
      const int pos8 = ((((ks << 2) | q)) ^ (l15 & 7)) * 8;
      short8 af[4], bfv[4];
      #pragma unroll
      for (int mt = 0; mt < 4; ++mt)
        af[mt] = *(const short8*)&As[(wm + 16 * mt + l15) * 64 + pos8];
      #pragma unroll
      for (int nt = 0; nt < 4; ++nt)
        bfv[nt] = *(const short8*)&Bs[(wn + 16 * nt + l15) * 64 + pos8];
      #pragma unroll
      for (int mt = 0; mt < 4; ++mt)
        #pragma unroll
        for (int nt = 0; nt < 4; ++nt)
          acc[mt][nt] = __builtin_amdgcn_mfma_f32_16x16x32_bf16(af[mt], bfv[nt], acc[mt][nt], 0, 0, 0);
    }
  }

  const int mwb = m0 + wm;
  const int nwb = n0 + wn;
  #pragma unroll
  for (int nt = 0; nt < 4; ++nt) {
    const int n = nwb + 16 * nt + l15;
    const float bv = (n < DIN) ? bias[n] : 0.f;
    float s1 = 0.f, s2 = 0.f;
    #pragma unroll
    for (int mt = 0; mt < 4; ++mt) {
      const int mb = mwb + 16 * mt + 4 * q;
      #pragma unroll
      for (int v = 0; v < 4; ++v) {
        const int m = mb + v;
        if (m < RROWS) {
          float val = acc[mt][nt][v] + bv;
          Y[(size_t)m * DP + n] = f2bf(val);
          s1 += val;
          s2 += val * val;
        }
      }
    }
    s1 += __shfl_xor(s1, 16);
    s2 += __shfl_xor(s2, 16);
    s1 += __shfl_xor(s1, 32);
    s2 += __shfl_xor(s2, 32);
    if (q == 0) {
      atomicAdd(&stats[n], s1);
      atomicAdd(&stats[DP + n], s2);
    }
  }
}

// ---------------------------------------------------------------------------
// ELT1: H = relu(gamma*(Y-mean)*istd + beta); zeroes the other stats buffer
// ---------------------------------------------------------------------------
__global__ __launch_bounds__(192) void elt_bn(
    const short* __restrict__ Yin, short* __restrict__ Hout,
    const float* __restrict__ stats, const float* __restrict__ gamma, const float* __restrict__ beta,
    float* __restrict__ zbuf) {
  int tid = threadIdx.x;
  if (blockIdx.x == 0)
    for (int z = tid; z < 2 * DP; z += 192) zbuf[z] = 0.f;
  int cg = tid % 48, rl = tid / 48;
  int c0 = cg * 8;
  float av[8], bb[8];
  #pragma unroll
  for (int j = 0; j < 8; ++j) {
    int c = c0 + j;
    float mean = stats[c] * (1.f / RROWS);
    float var = stats[DP + c] * (1.f / RROWS) - mean * mean;
    float istd = rsqrtf(var + BN_EPS);
    float g = (c < DIN) ? gamma[c] : 0.f;
    float b = (c < DIN) ? beta[c] : 0.f;
    av[j] = g * istd;
    bb[j] = b - g * istd * mean;
  }
  int row0 = blockIdx.x * 128;
  for (int rr = rl; rr < 128; rr += 4) {
    int row = row0 + rr;
    if (row >= RROWS) break;
    size_t off = (size_t)row * DP + c0;
    short8 y = *(const short8*)(Yin + off);
    short8 h;
    #pragma unroll
    for (int j = 0; j < 8; ++j) {
      float v = av[j] * bf2f(y[j]) + bb[j];
      h[j] = f2bf(fmaxf(v, 0.f));
    }
    *(short8*)(Hout + off) = h;
  }
}

// ---------------------------------------------------------------------------
// ELT2: X = relu(bn(Y) + X); optional fp32 write of result into d_out
// ---------------------------------------------------------------------------
__global__ __launch_bounds__(192) void elt_res(
    const short* __restrict__ Yin, short* __restrict__ X,
    const float* __restrict__ stats, const float* __restrict__ gamma, const float* __restrict__ beta,
    float* __restrict__ zbuf, float* __restrict__ fout) {
  int tid = threadIdx.x;
  if (blockIdx.x == 0)
    for (int z = tid; z < 2 * DP; z += 192) zbuf[z] = 0.f;
  int cg = tid % 48, rl = tid / 48;
  int c0 = cg * 8;
  float av[8], bb[8];
  #pragma unroll
  for (int j = 0; j < 8; ++j) {
    int c = c0 + j;
    float mean = stats[c] * (1.f / RROWS);
    float var = stats[DP + c] * (1.f / RROWS) - mean * mean;
    float istd = rsqrtf(var + BN_EPS);
    float g = (c < DIN) ? gamma[c] : 0.f;
    float b = (c < DIN) ? beta[c] : 0.f;
    av[j] = g * istd;
    bb[j] = b - g * istd * mean;
  }
  int row0 = blockIdx.x * 128;
  for (int rr = rl; rr < 128; rr += 4) {
    int row = row0 + rr;
    if (row >= RROWS) break;
    size_t off = (size_t)row * DP + c0;
    short8 y = *(const short8*)(Yin + off);
    short8 x = *(const short8*)(X + off);
    short8 h;
    float vr[8];
    #pragma unroll
    for (int j = 0; j < 8; ++j) {
      float v = av[j] * bf2f(y[j]) + bb[j] + bf2f(x[j]);
      v = fmaxf(v, 0.f);
      vr[j] = v;
      h[j] = f2bf(v);
    }
    *(short8*)(X + off) = h;
    if (fout != nullptr && c0 < DIN) {
      float4 o0 = make_float4(vr[0], vr[1], vr[2], vr[3]);
      float4 o1 = make_float4(vr[4], vr[5], vr[6], vr[7]);
      *(float4*)(fout + (size_t)row * DIN + c0) = o0;
      *(float4*)(fout + (size_t)row * DIN + c0 + 4) = o1;
    }
  }
}

// ---------------------------------------------------------------------------
// Fh GEMM (bf16 MFMA, split-K, LDS-transpose staging):
//   Fh[u][v] += sum_n E[n][u] * X[n][v]   per batch b
// grid: x = k-chunk (FH_S), y = v-tile (3 of 128), z = batch (8)
// LDS layout [row][72] shorts: 72-pad => ds_read_b128 16B-aligned, <=2-way banks
// ---------------------------------------------------------------------------
__global__ __launch_bounds__(256) void fh_mfma(const short* __restrict__ Eb, const short* __restrict__ X,
                                               float* __restrict__ Fh) {
  __shared__ short Es[128 * 72];
  __shared__ short Xs[128 * 72];
  const int tid = threadIdx.x;
  const int lane = tid & 63;
  const int w = tid >> 6;
  const int b = blockIdx.z;
  const int v0 = blockIdx.y * 128;
  const int chunk = (NVERT + FH_S - 1) / FH_S;  // 431
  const int kbase = blockIdx.x * chunk;
  const int nend = min(kbase + chunk, NVERT);
  const int np = tid & 31;   // n-pair index within 64-tile
  const int ug = tid >> 5;   // 0..7 -> u/v block of 16

  const short* Ebase = Eb + (size_t)b * NVERT * KDP;
  const short* Xbase = X + (size_t)b * NVERT * DP + v0;

  floatx4 acc[4][4];
  #pragma unroll
  for (int i = 0; i < 4; ++i)
    #pragma unroll
    for (int j = 0; j < 4; ++j)
      acc[i][j] = (floatx4){0.f, 0.f, 0.f, 0.f};

  const int l15 = lane & 15;
  const int q = lane >> 4;
  const int wm = 64 * (w >> 1);
  const int wn = 64 * (w & 1);

  const int ntiles = (nend - kbase + 63) >> 6;
  for (int kt = 0; kt < ntiles; ++kt) {
    const int nb = kbase + kt * 64;
    const int n0 = nb + 2 * np;
    const bool ok0 = (n0 < nend);
    const bool ok1 = (n0 + 1 < nend);
    __syncthreads();
    #pragma unroll
    for (int i = 0; i < 2; ++i) {
      const int u0 = ug * 16 + 8 * i;
      short8 z; 
      #pragma unroll
      for (int j = 0; j < 8; ++j) z[j] = 0;
      short8 e0 = z, e1 = z, x0 = z, x1 = z;
      if (ok0) {
        e0 = *(const short8*)(Ebase + (size_t)n0 * KDP + u0);
        x0 = *(const short8*)(Xbase + (size_t)n0 * DP + u0);
      }
      if (ok1) {
        e1 = *(const short8*)(Ebase + (size_t)(n0 + 1) * KDP + u0);
        x1 = *(const short8*)(Xbase + (size_t)(n0 + 1) * DP + u0);
      }
      #pragma unroll
      for (int j = 0; j < 8; ++j) {
        uint32_t ep = (uint32_t)(uint16_t)e0[j] | ((uint32_t)(uint16_t)e1[j] << 16);
        uint32_t xp = (uint32_t)(uint16_t)x0[j] | ((uint32_t)(uint16_t)x1[j] << 16);
        *(uint32_t*)&Es[(u0 + j) * 72 + 2 * np] = ep;
        *(uint32_t*)&Xs[(u0 + j) * 72 + 2 * np] = xp;
      }
    }
    __syncthreads();
    #pragma unroll
    for (int ks = 0; ks < 2; ++ks) {
      const int ko = ks * 32 + q * 8;
      short8 af[4], bfv[4];
      #pragma unroll
      for (int mt = 0; mt < 4; ++mt)
        af[mt] = *(const short8*)&Es[(wm + 16 * mt + l15) * 72 + ko];
      #pragma unroll
      for (int nt = 0; nt < 4; ++nt)
        bfv[nt] = *(const short8*)&Xs[(wn + 16 * nt + l15) * 72 + ko];
      #pragma unroll
      for (int mt = 0; mt < 4; ++mt)
        #pragma unroll
        for (int nt = 0; nt < 4; ++nt)
          acc[mt][nt] = __builtin_amdgcn_mfma_f32_16x16x32_bf16(af[mt], bfv[nt], acc[mt][nt], 0, 0, 0);
    }
  }

  float* Fo = Fh + (size_t)b * (KDP * DP);
  #pragma unroll
  for (int nt = 0; nt < 4; ++nt) {
    const int v = wn + 16 * nt + l15;
    #pragma unroll
    for (int mt = 0; mt < 4; ++mt) {
      const int ub = wm + 16 * mt + 4 * q;
      #pragma unroll
      for (int vi = 0; vi < 4; ++vi) {
        const int u = ub + vi;
        if (u < KD)
          atomicAdd(&Fo[(size_t)u * DP + v0 + v], acc[mt][nt][vi]);
      }
    }
  }
}

// ---------------------------------------------------------------------------
// Gram: mat0=FtF, mat1=FtG, mat2=GtG; Fh rows padded to DP=384 (pad cols are 0)
// ---------------------------------------------------------------------------
__global__ __launch_bounds__(256) void gram_kern(const float* __restrict__ Fh, float* __restrict__ G) {
  __shared__ float As[128 * 33];
  __shared__ float Bs[32 * 132];
  int mat = blockIdx.x, b = blockIdx.y;
  const float* Pa = Fh + (size_t)((mat == 2 ? BATCH : 0) + b) * KDP * DP;
  const float* Pb = Fh + (size_t)((mat == 0 ? 0 : BATCH) + b) * KDP * DP;
  int tid = threadIdx.x;
  int ty = tid >> 4, tx = tid & 15;
  float accv[8][8];
  #pragma unroll
  for (int i = 0; i < 8; ++i)
    #pragma unroll
    for (int j = 0; j < 8; ++j) accv[i][j] = 0.f;
  for (int ch = 0; ch < 12; ++ch) {
    int d0 = ch * 32;
    __syncthreads();
    #pragma unroll
    for (int j = 0; j < 16; ++j) {
      int e = tid + 256 * j;
      int r = e >> 5, c = e & 31;
      float va = (r < KD) ? Pa[(size_t)r * DP + d0 + c] : 0.f;
      float vb = (r < KD) ? Pb[(size_t)r * DP + d0 + c] : 0.f;
      As[r * 33 + c] = va;
      Bs[c * 132 + r] = vb;
    }
    __syncthreads();
    for (int dd = 0; dd < 32; ++dd) {
      float a[8], bv[8];
      #pragma unroll
      for (int i = 0; i < 8; ++i) a[i] = As[(8 * ty + i) * 33 + dd];
      float4 b0 = *(const float4*)&Bs[dd * 132 + 8 * tx];
      float4 b1 = *(const float4*)&Bs[dd * 132 + 8 * tx + 4];
      bv[0] = b0.x; bv[1] = b0.y; bv[2] = b0.z; bv[3] = b0.w;
      bv[4] = b1.x; bv[5] = b1.y; bv[6] = b1.z; bv[7] = b1.w;
      #pragma unroll
      for (int i = 0; i < 8; ++i)
        #pragma unroll
        for (int j = 0; j < 8; ++j)
          accv[i][j] += a[i] * bv[j];
    }
  }
  float* Go = G + (size_t)(b * 3 + mat) * KD * KD;
  #pragma unroll
  for (int i = 0; i < 8; ++i) {
    int k = 8 * ty + i;
    if (k < KD)
      #pragma unroll
      for (int j = 0; j < 8; ++j) {
        int l = 8 * tx + j;
        if (l < KD) Go[k * KD + l] = accv[i][j];
      }
  }
}

// ---------------------------------------------------------------------------
// Cholesky of FtF (sys even) / GtG (sys odd), in-LDS, L + invdiag to global
// ---------------------------------------------------------------------------
__global__ __launch_bounds__(128) void chol_kern(const float* __restrict__ G, float* __restrict__ Lb,
                                                 float* __restrict__ invd) {
  __shared__ float As[120 * 121];
  int sys = blockIdx.x;
  int b = sys >> 1;
  int mat = (sys & 1) ? 2 : 0;
  const float* Gm = G + (size_t)(b * 3 + mat) * KD * KD;
  int tid = threadIdx.x;
  for (int e = tid; e < KD * KD; e += 128) {
    int r = e / KD, c = e - r * KD;
    As[r * 121 + c] = Gm[e];
  }
  __syncthreads();
  for (int p = 0; p < KD; ++p) {
    if (tid == 0) As[p * 121 + p] = sqrtf(As[p * 121 + p]);
    __syncthreads();
    float dinv = 1.f / As[p * 121 + p];
    int i = p + 1 + tid;
    if (i < KD) As[i * 121 + p] *= dinv;
    __syncthreads();
    if (i < KD) {
      float lip = As[i * 121 + p];
      for (int jj = p + 1; jj <= i; ++jj)
        As[i * 121 + jj] -= lip * As[jj * 121 + p];
    }
    __syncthreads();
  }
  float* Lo = Lb + (size_t)sys * (KD * 121);
  for (int e = tid; e < KD * 121; e += 128) Lo[e] = As[e];
  if (tid < KD) invd[sys * KD + tid] = 1.f / As[tid * 121 + tid];
}

// ---------------------------------------------------------------------------
// Triangular solves: columns thread-private in LDS -> no barriers.
// ---------------------------------------------------------------------------
__global__ __launch_bounds__(128) void solve_kern(const float* __restrict__ Lb, const float* __restrict__ invd,
                                                  const float* __restrict__ G, float* __restrict__ out) {
  __shared__ float xs[120 * 128];
  int sys = blockIdx.x;
  int b = sys >> 1;
  int which = sys & 1;
  const float* L = Lb + (size_t)sys * (KD * 121);
  const float* iv = invd + sys * KD;
  const float* Bm = G + (size_t)(b * 3 + 1) * KD * KD;  // FtG
  int t = threadIdx.x;
  for (int k = 0; k < KD; ++k)
    xs[k * 128 + t] = (t < KD) ? (which == 0 ? Bm[k * KD + t] : Bm[t * KD + k]) : 0.f;
  for (int k = 0; k < KD; ++k) {
    float s0 = 0.f, s1 = 0.f, s2 = 0.f, s3 = 0.f;
    int j = 0;
    for (; j + 4 <= k; j += 4) {
      s0 += L[k * 121 + j + 0] * xs[(j + 0) * 128 + t];
      s1 += L[k * 121 + j + 1] * xs[(j + 1) * 128 + t];
      s2 += L[k * 121 + j + 2] * xs[(j + 2) * 128 + t];
      s3 += L[k * 121 + j + 3] * xs[(j + 3) * 128 + t];
    }
    for (; j < k; ++j) s0 += L[k * 121 + j] * xs[j * 128 + t];
    xs[k * 128 + t] = (xs[k * 128 + t] - ((s0 + s1) + (s2 + s3))) * iv[k];
  }
  for (int k = KD - 1; k >= 0; --k) {
    float s0 = 0.f, s1 = 0.f, s2 = 0.f, s3 = 0.f;
    int j = k + 1;
    for (; j + 4 <= KD; j += 4) {
      s0 += L[(j + 0) * 121 + k] * xs[(j + 0) * 128 + t];
      s1 += L[(j + 1) * 121 + k] * xs[(j + 1) * 128 + t];
      s2 += L[(j + 2) * 121 + k] * xs[(j + 2) * 128 + t];
      s3 += L[(j + 3) * 121 + k] * xs[(j + 3) * 128 + t];
    }
    for (; j < KD; ++j) s0 += L[j * 121 + k] * xs[j * 128 + t];
    xs[k * 128 + t] = (xs[k * 128 + t] - ((s0 + s1) + (s2 + s3))) * iv[k];
  }
  if (t < KD) {
    float* Co = out + (size_t)which * BATCH * KD * KD + (size_t)b * KD * KD;
    for (int k = 0; k < KD; ++k) Co[t * KD + k] = xs[k * 128 + t];
  }
}

// ---------------------------------------------------------------------------
extern "C" void kernel_launch(void* const* d_in, const int* in_sizes, int n_in,
                              void* d_out, int out_size, void* d_ws, size_t ws_size,
                              hipStream_t stream) {
  (void)in_sizes; (void)n_in; (void)out_size; (void)ws_size;
  const float* feat_x = (const float*)d_in[0];
  const float* feat_y = (const float*)d_in[1];
  const float* evecs_x = (const float*)d_in[2];
  const float* evecs_y = (const float*)d_in[3];
  const float* W1 = (const float*)d_in[4];
  const float* b1 = (const float*)d_in[5];
  const float* W2 = (const float*)d_in[6];
  const float* b2 = (const float*)d_in[7];
  const float* gamma = (const float*)d_in[8];
  const float* beta = (const float*)d_in[9];
  float* out = (float*)d_out;

  char* p = (char*)d_ws;
  auto carve = [&](size_t bytes) { char* r = p; p += (bytes + 255) & ~(size_t)255; return r; };
  short* W1t = (short*)carve(7ull * DP * DP * 2);
  short* W2t = (short*)carve(7ull * DP * DP * 2);
  short* X  = (short*)carve((size_t)RROWS * DP * 2);
  short* T1 = (short*)carve((size_t)RROWS * DP * 2);
  short* T2 = (short*)carve((size_t)RROWS * DP * 2);
  short* Eb = (short*)carve((size_t)BATCH * NVERT * KDP * 2);
  float* stats = (float*)carve(4ull * DP * 4);
  float* Fh = (float*)carve(2ull * BATCH * KDP * DP * 4);
  float* gram = (float*)carve((size_t)BATCH * 3 * KD * KD * 4);
  float* Lb = (float*)carve(16ull * KD * 121 * 4);
  float* invd = (float*)carve(16ull * KD * 4);
  float* statsA = stats;
  float* statsB = stats + 2 * DP;

  hipMemsetAsync(Fh, 0, 2ull * BATCH * KDP * DP * 4, stream);
  prep_w<<<dim3((7 * DP * DP) / 256, 2), 256, 0, stream>>>(W1, W2, W1t, W2t);

  const int MT = (RROWS + 127) / 128;  // 431
  const int ET = (NVERT * 16 + 255) / 256;  // 431
  for (int f = 0; f < 2; ++f) {
    const float* feat = f ? feat_y : feat_x;
    const float* ev = f ? evecs_y : evecs_x;
    float* fxo = out + 2 * BATCH * KD * KD + (size_t)f * RROWS * DIN;
    cast_in<<<MT, 192, 0, stream>>>(feat, X, statsA);
    cast_e<<<dim3(ET, BATCH), 256, 0, stream>>>(ev, Eb);
    for (int blk = 0; blk < NBLK; ++blk) {
      gemm_bn<<<dim3(MT, 3), 256, 0, stream>>>(X, W1t + (size_t)blk * DP * DP, T1, b1 + blk * DIN, statsA);
      elt_bn<<<MT, 192, 0, stream>>>(T1, T2, statsA, gamma + blk * DIN, beta + blk * DIN, statsB);
      gemm_bn<<<dim3(MT, 3), 256, 0, stream>>>(T2, W2t + (size_t)blk * DP * DP, T1, b2 + blk * DIN, statsB);
      elt_res<<<MT, 192, 0, stream>>>(T1, X, statsB, gamma + blk * DIN, beta + blk * DIN, statsA,
                                      (blk == NBLK - 1) ? fxo : (float*)nullptr);
    }
    fh_mfma<<<dim3(FH_S, 3, BATCH), 256, 0, stream>>>(Eb, X, Fh + (size_t)f * BATCH * KDP * DP);
  }
  gram_kern<<<dim3(3, BATCH), 256, 0, stream>>>(Fh, gram);
  chol_kern<<<16, 128, 0, stream>>>(gram, Lb, invd);
  solve_kern<<<16, 128, 0, stream>>>(Lb, invd, gram, out);
}